// Round 7
// baseline (7609.498 us; speedup 1.0000x reference)
//
#include <hip/hip_runtime.h>

typedef _Float16 f16;
typedef _Float16 f16x8 __attribute__((ext_vector_type(8)));
typedef float    f32x4 __attribute__((ext_vector_type(4)));

#define SEQ   2048
#define BATCH 64
#define EMBED 256
#define HID   256
#define NC    1024            // 4 gates * HID

// fast transcendentals (1-instr HW ops)
__device__ __forceinline__ float fexp2(float x){ float r; asm("v_exp_f32 %0, %1" : "=v"(r) : "v"(x)); return r; }
__device__ __forceinline__ float frcp (float x){ float r; asm("v_rcp_f32 %0, %1" : "=v"(r) : "v"(x)); return r; }
__device__ __forceinline__ float sigm_f(float y){ return frcp(1.f + fexp2(y * -1.44269504f)); }
__device__ __forceinline__ float tanh_f(float y){ return 2.f*frcp(1.f + fexp2(y * -2.88539009f)) - 1.f; }

__device__ __forceinline__ void gload_lds4(const void* g, void* s) {
  __builtin_amdgcn_global_load_lds((const __attribute__((address_space(1))) void*)g,
                                   (__attribute__((address_space(3))) void*)s, 4, 0, 0);
}

// ---------------------------------------------------------------------------
// prep_w: Wx_t/Wh_t [1024 col][256 k] f16 transposed; Wfrag = frag-packed
// LDS-resident W_h slice: [8 w][12 fi][64 lane][8 f16] where
//   fi<8  -> nt=5, kf=fi ;  fi>=8 -> nt=6, kf=fi-8   (per-wave col tiles)
//   col(nt,w,lr) = (nt>>1)*256 + w*32 + (nt&1)*16 + lr
// ---------------------------------------------------------------------------
__global__ __launch_bounds__(256) void prep_w(
    const float* __restrict__ Wix, const float* __restrict__ Wih,
    const float* __restrict__ Wfx, const float* __restrict__ Wfh,
    const float* __restrict__ Wgx, const float* __restrict__ Wgh,
    const float* __restrict__ Wox, const float* __restrict__ Woh,
    f16* __restrict__ Wx_t, f16* __restrict__ Wh_t, f16* __restrict__ Wfrag)
{
  int tid = blockIdx.x*256 + threadIdx.x;
  const float* WX[4] = {Wix, Wfx, Wgx, Wox};
  const float* WH[4] = {Wih, Wfh, Wgh, Woh};
  if (tid < 65536) {
    int which = tid >> 15;
    int j  = (tid >> 5) & 1023;
    int ko = tid & 31;
    const float* src = (which ? WH : WX)[j >> 8];
    int u = j & 255;
    f16x8 v;
    #pragma unroll
    for (int q = 0; q < 8; ++q) v[q] = (f16)src[(ko*8+q)*HID + u];
    *(f16x8*)((which ? Wh_t : Wx_t) + (size_t)j*256 + ko*8) = v;
  } else if (tid < 65536 + 6144) {
    int r  = tid - 65536;              // (w*12+fi)*64 + l
    int l  = r & 63;
    int fi = (r >> 6) % 12;
    int w  = r / 768;
    int nt = (fi < 8) ? 5 : 6;
    int kf = (fi < 8) ? fi : fi - 8;
    int col = (nt>>1)*256 + w*32 + (nt&1)*16 + (l & 15);
    int k0  = kf*32 + (l >> 4)*8;
    const float* src = WH[col >> 8];
    int u = col & 255;
    f16x8 v;
    #pragma unroll
    for (int q = 0; q < 8; ++q) v[q] = (f16)src[(k0+q)*HID + u];
    *(f16x8*)(Wfrag + (size_t)r*8) = v;
  }
}

// ---------------------------------------------------------------------------
// gemm_x (unchanged)
// ---------------------------------------------------------------------------
__global__ __launch_bounds__(256) void gemm_x(
    const float* __restrict__ emb, const f16* __restrict__ Bt,
    const float* __restrict__ b0, const float* __restrict__ b1,
    const float* __restrict__ b2, const float* __restrict__ b3,
    f16* __restrict__ Xo)
{
  __shared__ f16 Al[64*256];
  __shared__ f16 Bl[64*256];
  int wg = blockIdx.x;
  int R0 = (wg >> 4) * 64;
  int C0 = (wg & 15) * 64;
  int tid = threadIdx.x;

  #pragma unroll
  for (int j = 0; j < 8; ++j) {
    int c = tid + j*256; int row = c >> 5, ci = c & 31;
    const float* ap = emb + (size_t)(R0+row)*EMBED + ci*8;
    f32x4 a0 = *(const f32x4*)ap;
    f32x4 a1 = *(const f32x4*)(ap + 4);
    f16x8 v;
    #pragma unroll
    for (int q = 0; q < 4; ++q) { v[q] = (f16)a0[q]; v[q+4] = (f16)a1[q]; }
    *(f16x8*)((char*)Al + row*512 + ((ci*16) ^ ((row&7)<<4))) = v;
    f16x8 vb = *(const f16x8*)(Bt + (size_t)(C0+row)*256 + ci*8);
    *(f16x8*)((char*)Bl + row*512 + ((ci*16) ^ ((row&7)<<4))) = vb;
  }
  __syncthreads();

  int w = tid >> 6, l = tid & 63, lr = l & 15, lg = l >> 4;
  const float* bp = (C0 < 256) ? b0 : (C0 < 512) ? b1 : (C0 < 768) ? b2 : b3;
  int ub = (C0 & 255) + lr;
  f32x4 cf[4];
  #pragma unroll
  for (int nt = 0; nt < 4; ++nt) { float bv = bp[ub + nt*16]; cf[nt] = (f32x4){bv,bv,bv,bv}; }

  #pragma unroll
  for (int kf = 0; kf < 8; ++kf) {
    int arow = w*16 + lr;
    f16x8 af = *(const f16x8*)((char*)Al + arow*512 + ((kf*64 + lg*16) ^ ((arow&7)<<4)));
    #pragma unroll
    for (int nt = 0; nt < 4; ++nt) {
      int brow = nt*16 + lr;
      f16x8 bf = *(const f16x8*)((char*)Bl + brow*512 + ((kf*64 + lg*16) ^ ((brow&7)<<4)));
      cf[nt] = __builtin_amdgcn_mfma_f32_16x16x32_f16(af, bf, cf[nt], 0, 0, 0);
    }
  }
  #pragma unroll
  for (int nt = 0; nt < 4; ++nt)
    #pragma unroll
    for (int r = 0; r < 4; ++r) {
      int row = R0 + w*16 + lg*4 + r;
      int col = C0 + nt*16 + lr;
      Xo[(size_t)row*NC + col] = (f16)cf[nt][r];
    }
}

// ---------------------------------------------------------------------------
// lstm_rec: 64 WGs (1/batch), 512 thr (8 waves, 2/SIMD, 256-VGPR budget).
// Wave w, tile nt<8: col = (nt>>1)*256 + w*32 + (nt&1)*16 + lr. Lane lr<16
// owns units {w*32+lr, +16} all 4 gates -> lane-local c/h, 1 barrier/step.
// Weight frag sources per wave (64 frags):
//   REG 38: nt<4 all kf, nt==4 kf<6  -- WB[], loaded in prologue from Wh_t.
//     *** Wh_t is deliberately NON-const NON-restrict: with the in-loop
//     "memory" clobbers this makes remat of its loads ILLEGAL, which is
//     what defeated register residency in R3-R6 (const+restrict => compiler
//     legally re-streamed all weights from L2 every step). ***
//   LDS 12: nt==5, nt==6 kf<4  -- Wl 96 KB, filled once from Wfrag.
//   L2  14: nt==4 kf>=6, nt==6 kf>=4, nt==7  -- plain loads INSIDE the loop
//     (intended: L2 has headroom; their compiler-counted vmcnt waits also
//     drain older x prefetches, so x uses distance-4 prefetch to stay ahead).
// x: 5 rotating LDS buffers, prefetch t+4 via global_load_lds.
// Barrier: s_waitcnt lgkmcnt(0); s_barrier  (no vmcnt drain on the path).
// ---------------------------------------------------------------------------
__global__ __attribute__((amdgpu_flat_work_group_size(512,512), amdgpu_waves_per_eu(2,2)))
void lstm_rec(f16* Wh_t, const f16* __restrict__ Wfrag,
              const f16* __restrict__ X, float* out)
{
  __shared__ f16 Wl[8*12*64*8];    // 96 KB
  __shared__ f16 hbuf[2][256];     // 1 KB
  __shared__ f16 xl[5][1024];      // 10 KB rotating x buffers

  int b = blockIdx.x, tid = threadIdx.x;
  int w = tid >> 6, l = tid & 63, lr = l & 15, lg = l >> 4;

  // ---- prologue ----
  // x(0..3): one gload_lds4 per thread per buffer (wave w covers bytes [w*256,+256))
  #pragma unroll
  for (int q = 0; q < 4; ++q)
    gload_lds4(X + (size_t)(q*BATCH + b)*NC + w*128 + l*2, &xl[q][w*128]);

  // Wl fill (96 KB linear copy from frag-packed Wfrag)
  {
    const f16x8* srcp = (const f16x8*)Wfrag;
    f16x8* dstp = (f16x8*)Wl;
    #pragma unroll
    for (int i = 0; i < 12; ++i) dstp[tid + i*512] = srcp[tid + i*512];
  }
  // WB: 38 register frags from plain (non-const) Wh_t
  f16x8 WB[38];
  #pragma unroll
  for (int nt = 0; nt < 5; ++nt) {
    int col = (nt>>1)*256 + w*32 + (nt&1)*16 + lr;
    f16* basep = Wh_t + (size_t)col*256 + lg*8;
    #pragma unroll
    for (int kf = 0; kf < 8; ++kf)
      if (nt < 4 || kf < 6) WB[nt*8+kf] = *(f16x8*)(basep + kf*32);
  }
  #pragma unroll
  for (int i = 0; i < 38; ++i) asm volatile("" : "+v"(WB[i]));

  // per-lane base pointers for the in-loop (L2) weight classes
  f16* whb4 = Wh_t + (size_t)(2*256 + w*32 + 0*16 + lr)*256 + lg*8;  // nt=4
  f16* whb6 = Wh_t + (size_t)(3*256 + w*32 + 0*16 + lr)*256 + lg*8;  // nt=6
  f16* whb7 = Wh_t + (size_t)(3*256 + w*32 + 1*16 + lr)*256 + lg*8;  // nt=7

  if (tid < 256) ((unsigned*)hbuf)[tid] = 0;   // h(0)=0, both parities
  float cA = 0.f, cB = 0.f;

  asm volatile("s_waitcnt vmcnt(0) lgkmcnt(0)" ::: "memory");
  __builtin_amdgcn_s_barrier();

  int xc = 0;
  for (int t = 0; t < SEQ; ++t) {
    int cur = t & 1;
    // cf init from x_t
    const f16* xp = xl[xc];
    f32x4 cf[8];
    #pragma unroll
    for (int nt = 0; nt < 8; ++nt) {
      float xv = (float)xp[(nt>>1)*256 + w*32 + (nt&1)*16 + lr];
      cf[nt] = (f32x4){xv, xv, xv, xv};
    }
    // MFMA over K; B-operand source per (nt,kf) class (all statically folded)
    #pragma unroll
    for (int kf = 0; kf < 8; ++kf) {
      f16x8 ha = *(const f16x8*)(&hbuf[cur][kf*32 + lg*8]);
      #pragma unroll
      for (int nt = 0; nt < 8; ++nt) {
        f16x8 wb;
        if (nt < 4 || (nt == 4 && kf < 6)) {
          wb = WB[nt*8+kf];
        } else if (nt == 5 || (nt == 6 && kf < 4)) {
          int fi = (nt == 5) ? kf : 8 + kf;
          wb = *(const f16x8*)(&Wl[(size_t)((w*12 + fi)*64 + l)*8]);
        } else {
          f16* bp = (nt == 4) ? whb4 : (nt == 6) ? whb6 : whb7;
          wb = *(f16x8*)(bp + kf*32);
        }
        cf[nt] = __builtin_amdgcn_mfma_f32_16x16x32_f16(ha, wb, cf[nt], 0, 0, 0);
      }
    }
    // x prefetch t+4 (AFTER the in-loop weight loads: their counted vmcnt
    // waits must not drain this step's fresh prefetch)
    if (t + 4 < SEQ) {
      int xn = xc + 4; if (xn >= 5) xn -= 5;
      gload_lds4(X + ((size_t)(t+4)*BATCH + b)*NC + w*128 + l*2, &xl[xn][w*128]);
    }
    // lane-local activations + c/h update + stores (lanes l<16)
    if (l < 16) {
      float iA = sigm_f(cf[0][0]), iB = sigm_f(cf[1][0]);
      float fA = sigm_f(cf[2][0]), fB = sigm_f(cf[3][0]);
      float gA = tanh_f(cf[4][0]), gB = tanh_f(cf[5][0]);
      float oA = sigm_f(cf[6][0]), oB = sigm_f(cf[7][0]);
      cA = fA*cA + iA*gA;
      cB = fB*cB + iB*gB;
      float hA = oA*tanh_f(cA);
      float hB = oB*tanh_f(cB);
      int uA = w*32 + lr, uB = uA + 16;
      hbuf[cur^1][uA] = (f16)hA;
      hbuf[cur^1][uB] = (f16)hB;
      float* op = out + ((size_t)t*BATCH + b)*HID;
      op[uA] = hA;
      op[uB] = hB;
    }
    asm volatile("s_waitcnt lgkmcnt(0)" ::: "memory");
    __builtin_amdgcn_s_barrier();

    xc = (xc == 4) ? 0 : xc + 1;
  }
}

// ---------------------------------------------------------------------------
extern "C" void kernel_launch(void* const* d_in, const int* in_sizes, int n_in,
                              void* d_out, int out_size, void* d_ws, size_t ws_size,
                              hipStream_t stream) {
  const float* emb = (const float*)d_in[0];
  const float* Wix = (const float*)d_in[1];
  const float* Wih = (const float*)d_in[2];
  const float* bi  = (const float*)d_in[3];
  const float* Wfx = (const float*)d_in[4];
  const float* Wfh = (const float*)d_in[5];
  const float* bf  = (const float*)d_in[6];
  const float* Wgx = (const float*)d_in[7];
  const float* Wgh = (const float*)d_in[8];
  const float* bg  = (const float*)d_in[9];
  const float* Wox = (const float*)d_in[10];
  const float* Woh = (const float*)d_in[11];
  const float* bo  = (const float*)d_in[12];

  char* ws = (char*)d_ws;
  f16* Wx_t  = (f16*)(ws);                    //   524288 B
  f16* Wh_t  = (f16*)(ws + 524288);           //   524288 B
  f16* Wfrag = (f16*)(ws + 1048576);          //    98304 B
  f16* Xp    = (f16*)(ws + 1179648);          // 268435456 B

  prep_w  <<<280,   256, 0, stream>>>(Wix, Wih, Wfx, Wfh, Wgx, Wgh, Wox, Woh,
                                      Wx_t, Wh_t, Wfrag);
  gemm_x  <<<32768, 256, 0, stream>>>(emb, Wx_t, bi, bf, bg, bo, Xp);
  lstm_rec<<<64,    512, 0, stream>>>(Wh_t, Wfrag, Xp, (float*)d_out);
}